// Round 2
// baseline (1472.631 us; speedup 1.0000x reference)
//
#include <hip/hip_runtime.h>
#include <hip/hip_bf16.h>
#include <cstdint>
#include <cstddef>

// Problem dims (fixed)
#define SEQ 4096
#define DM  512
#define NH  8
#define DPH 64
#define FF  2048

using short8 = __attribute__((ext_vector_type(8))) short;
using f32x4  = __attribute__((ext_vector_type(4))) float;

__device__ inline float b2f(unsigned short u) {
    union { unsigned int i; float f; } c; c.i = ((unsigned int)u) << 16; return c.f;
}
__device__ inline unsigned short f2b(float f) {
    union { float f; unsigned int u; } c; c.f = f;
    unsigned int u = c.u;
    return (unsigned short)((u + 0x7fffu + ((u >> 16) & 1u)) >> 16);
}

// ---------------------------------------------------------------------------
// bf16 MFMA GEMM: C[m][n] = scale * sum_k A[m][k] * BT[n][k]  (+bias, +res, relu)
// A: [M,K] row-major (bf16, or fp32 converted on load if AF32); BT: [N,K] bf16.
// Each wave computes a 16(m) x 64(n) strip; block = 4 waves stacked on m.
// grid = (N/64, M/64, batch)
// ---------------------------------------------------------------------------
template<int AF32>
__global__ __launch_bounds__(256) void gemm_kernel(
    const void* __restrict__ Av, const unsigned short* __restrict__ BT,
    const float* __restrict__ bias, const unsigned short* __restrict__ res,
    unsigned short* __restrict__ Cb, float* __restrict__ Cf,
    int M, int N, int K, long sA, long sB, long sC, float scale, int relu)
{
    const long z = blockIdx.z;
    BT += z * sB;
    const long co = z * sC;

    const int lane = threadIdx.x & 63;
    const int wid  = threadIdx.x >> 6;
    const int quad = lane >> 4;
    const int col  = lane & 15;
    const int m0 = blockIdx.y * 64 + wid * 16;
    const int n0 = blockIdx.x * 64;

    f32x4 acc[4];
    const f32x4 zero4 = {0.f, 0.f, 0.f, 0.f};
#pragma unroll
    for (int t = 0; t < 4; ++t) acc[t] = zero4;

    const unsigned short* arow16 = nullptr;
    const float*          arow32 = nullptr;
    if (AF32) arow32 = (const float*)Av          + z * sA + (size_t)(m0 + col) * K + quad * 8;
    else      arow16 = (const unsigned short*)Av + z * sA + (size_t)(m0 + col) * K + quad * 8;
    const unsigned short* brow = BT + (size_t)(n0 + col) * K + quad * 8;

    for (int k0 = 0; k0 < K; k0 += 32) {
        short8 a;
        if (AF32) {
            const float4 f0 = *(const float4*)(arow32 + k0);
            const float4 f1 = *(const float4*)(arow32 + k0 + 4);
            a[0] = (short)f2b(f0.x); a[1] = (short)f2b(f0.y);
            a[2] = (short)f2b(f0.z); a[3] = (short)f2b(f0.w);
            a[4] = (short)f2b(f1.x); a[5] = (short)f2b(f1.y);
            a[6] = (short)f2b(f1.z); a[7] = (short)f2b(f1.w);
        } else {
            a = *(const short8*)(arow16 + k0);
        }
#pragma unroll
        for (int t = 0; t < 4; ++t) {
            short8 b = *(const short8*)(brow + (size_t)t * 16 * K + k0);
            acc[t] = __builtin_amdgcn_mfma_f32_16x16x32_bf16(a, b, acc[t], 0, 0, 0);
        }
    }

#pragma unroll
    for (int t = 0; t < 4; ++t) {
        const int n = n0 + t * 16 + col;
        const float bv = bias ? bias[n] : 0.f;
#pragma unroll
        for (int r = 0; r < 4; ++r) {
            const int row = m0 + quad * 4 + r;
            float v = acc[t][r] * scale + bv;
            const size_t idx = (size_t)row * N + n;
            if (res)  v += b2f(res[idx]);
            if (relu) v = fmaxf(v, 0.f);
            if (Cf) Cf[co + idx] = v;
            else    Cb[co + idx] = f2b(v);
        }
    }
}

// ---------------------------------------------------------------------------
// fp32 -> bf16 transpose (weights): dst[c][r] = (bf16)src[r][c]
// grid=(C/32, R/32); block=256
// ---------------------------------------------------------------------------
__global__ __launch_bounds__(256) void transpose_cast_kernel(
    const float* __restrict__ src, unsigned short* __restrict__ dst, int R, int C)
{
    __shared__ float tile[32][33];
    const int c0 = blockIdx.x * 32, r0 = blockIdx.y * 32;
    const int tx = threadIdx.x & 31, ty = threadIdx.x >> 5;  // 32 x 8
#pragma unroll
    for (int i = 0; i < 4; ++i)
        tile[ty + i * 8][tx] = src[(size_t)(r0 + ty + i * 8) * C + c0 + tx];
    __syncthreads();
#pragma unroll
    for (int i = 0; i < 4; ++i)
        dst[(size_t)(c0 + ty + i * 8) * R + r0 + tx] = f2b(tile[tx][ty + i * 8]);
}

// ---------------------------------------------------------------------------
// bf16 transpose (per-head V): dst[c][r] = src[r][c]; grid=(C/32, R/32, batch)
// ---------------------------------------------------------------------------
__global__ __launch_bounds__(256) void transpose_kernel(
    const unsigned short* __restrict__ src, unsigned short* __restrict__ dst,
    int R, int C)
{
    __shared__ unsigned short tile[32][33];
    const long off = (long)blockIdx.z * (long)R * (long)C;
    src += off; dst += off;
    const int c0 = blockIdx.x * 32, r0 = blockIdx.y * 32;
    const int tx = threadIdx.x & 31, ty = threadIdx.x >> 5;
#pragma unroll
    for (int i = 0; i < 4; ++i)
        tile[ty + i * 8][tx] = src[(size_t)(r0 + ty + i * 8) * C + c0 + tx];
    __syncthreads();
#pragma unroll
    for (int i = 0; i < 4; ++i)
        dst[(size_t)(c0 + ty + i * 8) * R + r0 + tx] = tile[tx][ty + i * 8];
}

// ---------------------------------------------------------------------------
// fp32 -> bf16 elementwise cast (x). n4 = elements/4.
// ---------------------------------------------------------------------------
__global__ __launch_bounds__(256) void cast_kernel(
    const float* __restrict__ src, unsigned short* __restrict__ dst, int n4)
{
    const int i = blockIdx.x * 256 + threadIdx.x;
    if (i >= n4) return;
    const float4 v = ((const float4*)src)[i];
    union { unsigned short s[4]; unsigned long long u; } p;
    p.s[0] = f2b(v.x); p.s[1] = f2b(v.y); p.s[2] = f2b(v.z); p.s[3] = f2b(v.w);
    ((unsigned long long*)dst)[i] = p.u;
}

// ---------------------------------------------------------------------------
// In-place fp32 row softmax, rows of 4096. One block (256 thr) per row.
// ---------------------------------------------------------------------------
__global__ __launch_bounds__(256) void softmax_kernel(float* __restrict__ att)
{
    __shared__ float red[4];
    float* p = att + (size_t)blockIdx.x * 4096;
    const int t = threadIdx.x;
    const int w = t >> 6, lane = t & 63;

    float4 v4[4];
#pragma unroll
    for (int i = 0; i < 4; ++i) v4[i] = *(const float4*)(p + t * 16 + i * 4);
    float* v = (float*)v4;

    float m = v[0];
#pragma unroll
    for (int i = 1; i < 16; ++i) m = fmaxf(m, v[i]);
#pragma unroll
    for (int off = 32; off; off >>= 1) m = fmaxf(m, __shfl_xor(m, off));
    if (lane == 0) red[w] = m;
    __syncthreads();
    m = fmaxf(fmaxf(red[0], red[1]), fmaxf(red[2], red[3]));
    __syncthreads();

    float s = 0.f;
#pragma unroll
    for (int i = 0; i < 16; ++i) { v[i] = __expf(v[i] - m); s += v[i]; }
#pragma unroll
    for (int off = 32; off; off >>= 1) s += __shfl_xor(s, off);
    if (lane == 0) red[w] = s;
    __syncthreads();
    s = red[0] + red[1] + red[2] + red[3];
    const float inv = 1.f / s;

#pragma unroll
    for (int i = 0; i < 16; ++i) v[i] *= inv;
#pragma unroll
    for (int i = 0; i < 4; ++i) *(float4*)(p + t * 16 + i * 4) = v4[i];
}

// ---------------------------------------------------------------------------
// LayerNorm over rows of 512 fp32 -> fp32 out. One block (256 thr) per row.
// ---------------------------------------------------------------------------
__global__ __launch_bounds__(256) void ln_kernel(
    const float* __restrict__ pre,
    const float* __restrict__ gamma, const float* __restrict__ beta,
    float* __restrict__ out)
{
    __shared__ float redS[4], redQ[4];
    const float* p = pre + (size_t)blockIdx.x * 512;
    const int t = threadIdx.x;
    const int w = t >> 6, lane = t & 63;

    const float2 xv = *(const float2*)(p + t * 2);
    float s = xv.x + xv.y;
    float q = xv.x * xv.x + xv.y * xv.y;
#pragma unroll
    for (int off = 32; off; off >>= 1) {
        s += __shfl_xor(s, off);
        q += __shfl_xor(q, off);
    }
    if (lane == 0) { redS[w] = s; redQ[w] = q; }
    __syncthreads();
    s = redS[0] + redS[1] + redS[2] + redS[3];
    q = redQ[0] + redQ[1] + redQ[2] + redQ[3];

    const float mu  = s * (1.f / 512.f);
    const float var = q * (1.f / 512.f) - mu * mu;
    const float rs  = rsqrtf(var + 1e-5f);

    const size_t o = (size_t)blockIdx.x * 512 + t * 2;
    out[o]     = (xv.x - mu) * rs * gamma[t * 2]     + beta[t * 2];
    out[o + 1] = (xv.y - mu) * rs * gamma[t * 2 + 1] + beta[t * 2 + 1];
}

// ---------------------------------------------------------------------------
extern "C" void kernel_launch(void* const* d_in, const int* in_sizes, int n_in,
                              void* d_out, int out_size, void* d_ws, size_t ws_size,
                              hipStream_t stream)
{
    (void)in_sizes; (void)n_in; (void)out_size; (void)ws_size;

    const float* x     = (const float*)d_in[0];
    const float* wq    = (const float*)d_in[1];
    const float* bq    = (const float*)d_in[2];
    const float* wk    = (const float*)d_in[3];
    const float* bk    = (const float*)d_in[4];
    const float* wv    = (const float*)d_in[5];
    const float* bv    = (const float*)d_in[6];
    const float* wo    = (const float*)d_in[7];
    const float* bo    = (const float*)d_in[8];
    const float* w1    = (const float*)d_in[9];
    const float* b1    = (const float*)d_in[10];
    const float* w2    = (const float*)d_in[11];
    const float* b2    = (const float*)d_in[12];
    const float* gamma = (const float*)d_in[13];
    const float* beta  = (const float*)d_in[14];

    float* out = (float*)d_out;
    float* att = out + (size_t)SEQ * DM;  // attn region: 8*4096*4096 fp32

    char* wsp = (char*)d_ws;
    auto alloc = [&](size_t bytes) {
        char* p = wsp;
        wsp += (bytes + 255) & ~(size_t)255;
        return p;
    };
    unsigned short* wqT  = (unsigned short*)alloc((size_t)DM * DM * 2);
    unsigned short* wkT  = (unsigned short*)alloc((size_t)DM * DM * 2);
    unsigned short* wvT  = (unsigned short*)alloc((size_t)DM * DM * 2);
    unsigned short* woT  = (unsigned short*)alloc((size_t)DM * DM * 2);
    unsigned short* w1T  = (unsigned short*)alloc((size_t)DM * FF * 2);
    unsigned short* w2T  = (unsigned short*)alloc((size_t)FF * DM * 2);
    unsigned short* xb   = (unsigned short*)alloc((size_t)SEQ * DM * 2);
    unsigned short* qb   = (unsigned short*)alloc((size_t)SEQ * DM * 2);
    unsigned short* kb   = (unsigned short*)alloc((size_t)SEQ * DM * 2);
    unsigned short* vb   = (unsigned short*)alloc((size_t)SEQ * DM * 2);
    unsigned short* vT   = (unsigned short*)alloc((size_t)SEQ * DM * 2);
    unsigned short* ctx  = (unsigned short*)alloc((size_t)SEQ * DM * 2);
    unsigned short* aout = (unsigned short*)alloc((size_t)SEQ * DM * 2);
    unsigned short* ffn1 = (unsigned short*)alloc((size_t)SEQ * FF * 2);
    float*          pre  = (float*)alloc((size_t)SEQ * DM * 4);

    const dim3 blk(256);

    // x -> bf16
    cast_kernel<<<dim3((SEQ * DM / 4 + 255) / 256), blk, 0, stream>>>(x, xb, SEQ * DM / 4);

    // Weight transposes+casts -> [out,in] row-major bf16 (BT form)
    transpose_cast_kernel<<<dim3(16, 16), blk, 0, stream>>>(wq, wqT, DM, DM);
    transpose_cast_kernel<<<dim3(16, 16), blk, 0, stream>>>(wk, wkT, DM, DM);
    transpose_cast_kernel<<<dim3(16, 16), blk, 0, stream>>>(wv, wvT, DM, DM);
    transpose_cast_kernel<<<dim3(16, 16), blk, 0, stream>>>(wo, woT, DM, DM);
    transpose_cast_kernel<<<dim3(64, 16), blk, 0, stream>>>(w1, w1T, DM, FF);
    transpose_cast_kernel<<<dim3(16, 64), blk, 0, stream>>>(w2, w2T, FF, DM);

    // Q/K/V projections: [4096,512] = x @ W + b (bf16 out)
    gemm_kernel<0><<<dim3(8, 64, 1), blk, 0, stream>>>(xb, wqT, bq, nullptr, qb, nullptr,
                                                       SEQ, DM, DM, 0, 0, 0, 1.f, 0);
    gemm_kernel<0><<<dim3(8, 64, 1), blk, 0, stream>>>(xb, wkT, bk, nullptr, kb, nullptr,
                                                       SEQ, DM, DM, 0, 0, 0, 1.f, 0);
    gemm_kernel<0><<<dim3(8, 64, 1), blk, 0, stream>>>(xb, wvT, bv, nullptr, vb, nullptr,
                                                       SEQ, DM, DM, 0, 0, 0, 1.f, 0);

    // Per-head V transpose: [4096,64] -> [64,4096], batch=8
    transpose_kernel<<<dim3(2, 128, 8), blk, 0, stream>>>(vb, vT, SEQ, DPH);

    // Scores: att[h] = (Qh @ Kh^T) / 8  (fp32 straight into d_out attn region)
    gemm_kernel<0><<<dim3(64, 64, 8), blk, 0, stream>>>(qb, kb, nullptr, nullptr, nullptr, att,
                                                        SEQ, SEQ, DPH,
                                                        (long)SEQ * DPH, (long)SEQ * DPH,
                                                        (long)SEQ * SEQ, 0.125f, 0);

    // Softmax in place (fp32, 8*4096 rows)
    softmax_kernel<<<dim3(NH * SEQ), blk, 0, stream>>>(att);

    // Context: ctx[h] = att[h] @ Vh  (fp32 A converted on load, bf16 out)
    gemm_kernel<1><<<dim3(1, 64, 8), blk, 0, stream>>>(att, vT, nullptr, nullptr, ctx, nullptr,
                                                       SEQ, DPH, SEQ,
                                                       (long)SEQ * SEQ, (long)SEQ * DPH,
                                                       (long)SEQ * DPH, 1.f, 0);

    // attn_out = ctx @ wo + bo + x
    gemm_kernel<0><<<dim3(8, 64, 1), blk, 0, stream>>>(ctx, woT, bo, xb, aout, nullptr,
                                                       SEQ, DM, DM, 0, 0, 0, 1.f, 0);

    // ffn1 = relu(attn_out @ w1 + b1)
    gemm_kernel<0><<<dim3(32, 64, 1), blk, 0, stream>>>(aout, w1T, b1, nullptr, ffn1, nullptr,
                                                        SEQ, FF, DM, 0, 0, 0, 1.f, 1);

    // pre-LN = ffn1 @ w2 + b2 + attn_out (fp32)
    gemm_kernel<0><<<dim3(8, 64, 1), blk, 0, stream>>>(ffn1, w2T, b2, aout, nullptr, pre,
                                                       SEQ, DM, FF, 0, 0, 0, 1.f, 0);

    // LayerNorm -> out (fp32)
    ln_kernel<<<dim3(SEQ), blk, 0, stream>>>(pre, gamma, beta, out);
}